// Round 1
// baseline (135.051 us; speedup 1.0000x reference)
//
#include <hip/hip_runtime.h>
#include <stdint.h>

typedef _Float16 f16;
typedef __attribute__((ext_vector_type(2))) _Float16 f16x2;
typedef __attribute__((ext_vector_type(4))) _Float16 f16x4;
typedef __attribute__((ext_vector_type(8))) _Float16 f16x8;
typedef __attribute__((ext_vector_type(4))) float f32x4;

#define H0 64
#define W0 128
#define NPIX 8192   // H0*W0
#define KDIM 256

// ---------------------------------------------------------------------------
// 1) transpose + fp32->fp16: in [256][8192] (d-major) -> out [8192][256]
// ---------------------------------------------------------------------------
__global__ __launch_bounds__(256) void transpose_cvt(const float* __restrict__ in,
                                                     f16* __restrict__ out) {
  __shared__ f16 tile[64][65];
  int t = threadIdx.x;
  int m0 = blockIdx.x * 64;   // 128 m-tiles
  int d0 = blockIdx.y * 64;   // 4 d-tiles
  int a = t & 63;             // fast index within wave
  int b = t >> 6;             // wave id 0..3
#pragma unroll
  for (int i = 0; i < 16; ++i) {
    int d = b + i * 4;
    tile[a][d] = (f16)in[(size_t)(d0 + d) * NPIX + m0 + a];   // coalesced read along m
  }
  __syncthreads();
#pragma unroll
  for (int i = 0; i < 16; ++i) {
    int m = b + i * 4;
    out[(size_t)(m0 + m) * KDIM + d0 + a] = tile[m][a];       // coalesced write along d
  }
}

// ---------------------------------------------------------------------------
// 2) GEMM: C[m][n] = (1/16) * sum_k A[m][k]*B[n][k],  M=N=8192, K=256, f16 out
//    m97 structure: 128x128 tile, 4 waves (2x2), 4x4 16x16x32 frags/wave,
//    global_load_lds width-16 staging, 2 barriers per K-step.
// ---------------------------------------------------------------------------
#define GLD16(gp, lp)                                                          \
  __builtin_amdgcn_global_load_lds(                                            \
      (const __attribute__((address_space(1))) void*)(gp),                     \
      (__attribute__((address_space(3))) void*)(lp), 16, 0, 0)

__global__ __launch_bounds__(256) void corr_gemm(const f16* __restrict__ A,
                                                 const f16* __restrict__ B,
                                                 f16* __restrict__ C) {
  __shared__ f16 sA[128 * 32];   // [row][k] linear, 8KB
  __shared__ f16 sB[128 * 32];

  int bid = blockIdx.x;                       // 4096 blocks (64x64)
  int swz = ((bid & 7) << 9) | (bid >> 3);    // XCD swizzle, bijective (4096%8==0)
  int bm = (swz >> 6) << 7;
  int bn = (swz & 63) << 7;

  int t = threadIdx.x;
  int lane = t & 63;
  int w = t >> 6;                 // wave 0..3
  int wm = (w >> 1) * 64;
  int wn = (w & 1) * 64;
  int lr = lane & 15;             // fragment row (A) / col (B)
  int ko = lane >> 4;             // k-octet 0..3

  const f16* Ab = A + (size_t)bm * KDIM;
  const f16* Bb = B + (size_t)bn * KDIM;
  int r  = t >> 2;                // staging row 0..63
  int kc = (t & 3) * 8;           // staging k-slot

  f32x4 acc[4][4];
#pragma unroll
  for (int i = 0; i < 4; ++i)
#pragma unroll
    for (int j = 0; j < 4; ++j) acc[i][j] = (f32x4){0.f, 0.f, 0.f, 0.f};

#pragma unroll
  for (int k0 = 0; k0 < KDIM; k0 += 32) {
    // stage A,B tiles: thread t covers LDS bytes [t*16, t*16+16) per instr
    GLD16(Ab + (size_t)r * KDIM + k0 + kc,        sA + t * 8);
    GLD16(Ab + (size_t)(r + 64) * KDIM + k0 + kc, sA + 2048 + t * 8);
    GLD16(Bb + (size_t)r * KDIM + k0 + kc,        sB + t * 8);
    GLD16(Bb + (size_t)(r + 64) * KDIM + k0 + kc, sB + 2048 + t * 8);
    __syncthreads();   // drains vmcnt -> LDS tiles valid

    f16x8 af[4], bf[4];
#pragma unroll
    for (int i = 0; i < 4; ++i) {
      af[i] = *(const f16x8*)(sA + (wm + i * 16 + lr) * 32 + ko * 8);
      bf[i] = *(const f16x8*)(sB + (wn + i * 16 + lr) * 32 + ko * 8);
    }
#pragma unroll
    for (int mi = 0; mi < 4; ++mi)
#pragma unroll
      for (int ni = 0; ni < 4; ++ni)
        acc[mi][ni] = __builtin_amdgcn_mfma_f32_16x16x32_f16(af[mi], bf[ni],
                                                             acc[mi][ni], 0, 0, 0);
    __syncthreads();   // all reads done before next-iter staging overwrites
  }

  // epilogue: D[row=ko*4+r2][col=lr] per fragment, scale 1/sqrt(256)
#pragma unroll
  for (int mi = 0; mi < 4; ++mi)
#pragma unroll
    for (int ni = 0; ni < 4; ++ni)
#pragma unroll
      for (int r2 = 0; r2 < 4; ++r2) {
        int row = bm + wm + mi * 16 + ko * 4 + r2;
        int col = bn + wn + ni * 16 + lr;
        C[(size_t)row * NPIX + col] = (f16)(acc[mi][ni][r2] * 0.0625f);
      }
}

// ---------------------------------------------------------------------------
// 3) fused pyramid pooling: thread owns an 8x8 block of L0 for one row m,
//    emits 4x4 of L1, 2x2 of L2, 1 of L3 (all 2x2 means, fp32 accum)
// ---------------------------------------------------------------------------
__global__ __launch_bounds__(256) void pool_all(const f16* __restrict__ L0,
                                                f16* __restrict__ L1,
                                                f16* __restrict__ L2,
                                                f16* __restrict__ L3) {
  int idx = blockIdx.x * 256 + threadIdx.x;  // 8192*8*16 = 1,048,576
  int x3 = idx & 15;
  int y3 = (idx >> 4) & 7;
  int n  = idx >> 7;
  const f16* base = L0 + (size_t)n * NPIX + y3 * 8 * W0 + x3 * 8;

  float v[8][8];
#pragma unroll
  for (int rr = 0; rr < 8; ++rr) {
    f16x8 row = *(const f16x8*)(base + rr * W0);   // 16B coalesced
#pragma unroll
    for (int cc = 0; cc < 8; ++cc) v[rr][cc] = (float)row[cc];
  }

  float l1[4][4];
#pragma unroll
  for (int rr = 0; rr < 4; ++rr)
#pragma unroll
    for (int cc = 0; cc < 4; ++cc)
      l1[rr][cc] = 0.25f * (v[2*rr][2*cc] + v[2*rr][2*cc+1] +
                            v[2*rr+1][2*cc] + v[2*rr+1][2*cc+1]);
#pragma unroll
  for (int rr = 0; rr < 4; ++rr) {
    f16x4 o = {(f16)l1[rr][0], (f16)l1[rr][1], (f16)l1[rr][2], (f16)l1[rr][3]};
    *(f16x4*)(L1 + ((size_t)n * 32 + y3 * 4 + rr) * 64 + x3 * 4) = o;
  }

  float l2[2][2];
#pragma unroll
  for (int rr = 0; rr < 2; ++rr)
#pragma unroll
    for (int cc = 0; cc < 2; ++cc)
      l2[rr][cc] = 0.25f * (l1[2*rr][2*cc] + l1[2*rr][2*cc+1] +
                            l1[2*rr+1][2*cc] + l1[2*rr+1][2*cc+1]);
#pragma unroll
  for (int rr = 0; rr < 2; ++rr) {
    f16x2 o = {(f16)l2[rr][0], (f16)l2[rr][1]};
    *(f16x2*)(L2 + ((size_t)n * 16 + y3 * 2 + rr) * 32 + x3 * 2) = o;
  }

  float l3 = 0.25f * (l2[0][0] + l2[0][1] + l2[1][0] + l2[1][1]);
  L3[((size_t)n * 8 + y3) * 16 + x3] = (f16)l3;
}

// ---------------------------------------------------------------------------
// 4) bilinear window sampling: thread = (pixel m, level); all 81 samples share
//    one fractional offset -> 10x10 corner grid, streamed 2 rows at a time.
//    out[c][m] with c = lev*81 + j*9 + i  (coalesced stores along m)
// ---------------------------------------------------------------------------
__global__ __launch_bounds__(256) void corr_sample(const f16* __restrict__ P0,
                                                   const f16* __restrict__ P1,
                                                   const f16* __restrict__ P2,
                                                   const f16* __restrict__ P3,
                                                   const float* __restrict__ coords,
                                                   float* __restrict__ out) {
  int t = blockIdx.x * 256 + threadIdx.x;  // 32768
  int m = t & (NPIX - 1);
  int lev = t >> 13;                       // wave-uniform
  const f16* P; int Hl, Wl;
  if (lev == 0)      { P = P0; Hl = 64; Wl = 128; }
  else if (lev == 1) { P = P1; Hl = 32; Wl = 64; }
  else if (lev == 2) { P = P2; Hl = 16; Wl = 32; }
  else               { P = P3; Hl = 8;  Wl = 16; }

  float cx = coords[m];
  float cy = coords[NPIX + m];
  float inv = 1.0f / (float)(1 << lev);
  float xb = cx * inv, yb = cy * inv;
  float fx = floorf(xb), fy = floorf(yb);
  int X0 = (int)fx - 4, Y0 = (int)fy - 4;
  float wx1 = xb - fx, wx0 = 1.0f - wx1;
  float wy1 = yb - fy, wy0 = 1.0f - wy1;

  const f16* base = P + (size_t)m * Hl * Wl;
  float* op = out + (size_t)lev * 81 * NPIX + m;

  float cur[10], nxt[10];
  auto loadrow = [&](float* row, int y) {
    bool yin = (y >= 0) && (y < Hl);
    const f16* rp = base + y * Wl;
#pragma unroll
    for (int i = 0; i < 10; ++i) {
      int x = X0 + i;
      row[i] = (yin && x >= 0 && x < Wl) ? (float)rp[x] : 0.0f;
    }
  };

  loadrow(cur, Y0);
#pragma unroll
  for (int j = 0; j < 9; ++j) {
    loadrow(nxt, Y0 + j + 1);
#pragma unroll
    for (int i = 0; i < 9; ++i) {
      float v = wy0 * (wx0 * cur[i] + wx1 * cur[i + 1])
              + wy1 * (wx0 * nxt[i] + wx1 * nxt[i + 1]);
      op[(size_t)(j * 9 + i) * NPIX] = v;
    }
#pragma unroll
    for (int i = 0; i < 10; ++i) cur[i] = nxt[i];
  }
}

// ---------------------------------------------------------------------------
extern "C" void kernel_launch(void* const* d_in, const int* in_sizes, int n_in,
                              void* d_out, int out_size, void* d_ws, size_t ws_size,
                              hipStream_t stream) {
  const float* fmap1  = (const float*)d_in[0];   // [1,256,64,128]
  const float* fmap2  = (const float*)d_in[1];
  const float* coords = (const float*)d_in[2];   // [1,2,64,128]
  float* out = (float*)d_out;                    // [1,324,64,128] fp32

  char* ws = (char*)d_ws;
  size_t offA  = 0;
  size_t offB  = offA  + (size_t)NPIX * KDIM * 2;      // 4 MB
  size_t offL0 = offB  + (size_t)NPIX * KDIM * 2;      // 8 MB
  size_t offL1 = offL0 + (size_t)NPIX * NPIX * 2;      // +128 MB
  size_t offL2 = offL1 + (size_t)NPIX * 2048 * 2;      // +32 MB
  size_t offL3 = offL2 + (size_t)NPIX * 512 * 2;       // +8 MB
  size_t need  = offL3 + (size_t)NPIX * 128 * 2;       // +2 MB  => ~187 MB
  if (ws_size < need) return;  // insufficient scratch

  f16* A  = (f16*)(ws + offA);
  f16* B  = (f16*)(ws + offB);
  f16* L0 = (f16*)(ws + offL0);
  f16* L1 = (f16*)(ws + offL1);
  f16* L2 = (f16*)(ws + offL2);
  f16* L3 = (f16*)(ws + offL3);

  transpose_cvt<<<dim3(128, 4), 256, 0, stream>>>(fmap1, A);
  transpose_cvt<<<dim3(128, 4), 256, 0, stream>>>(fmap2, B);
  corr_gemm<<<4096, 256, 0, stream>>>(A, B, L0);
  pool_all<<<4096, 256, 0, stream>>>(L0, L1, L2, L3);
  corr_sample<<<128, 256, 0, stream>>>(L0, L1, L2, L3, coords, out);
}

// Round 2
// 122.736 us; speedup vs baseline: 1.1003x; 1.1003x over previous
//
#include <hip/hip_runtime.h>
#include <stdint.h>

typedef _Float16 f16;
typedef __attribute__((ext_vector_type(2))) _Float16 f16x2;
typedef __attribute__((ext_vector_type(4))) _Float16 f16x4;
typedef __attribute__((ext_vector_type(8))) _Float16 f16x8;
typedef __attribute__((ext_vector_type(4))) float f32x4;

#define H0 64
#define W0 128
#define NPIX 8192   // H0*W0
#define KDIM 256

// ---------------------------------------------------------------------------
// 1) transpose + fp32->fp16: in [256][8192] (d-major) -> out [8192][256]
// ---------------------------------------------------------------------------
__global__ __launch_bounds__(256) void transpose_cvt(const float* __restrict__ in,
                                                     f16* __restrict__ out) {
  __shared__ f16 tile[64][65];
  int t = threadIdx.x;
  int m0 = blockIdx.x * 64;   // 128 m-tiles
  int d0 = blockIdx.y * 64;   // 4 d-tiles
  int a = t & 63;
  int b = t >> 6;
#pragma unroll
  for (int i = 0; i < 16; ++i) {
    int d = b + i * 4;
    tile[a][d] = (f16)in[(size_t)(d0 + d) * NPIX + m0 + a];
  }
  __syncthreads();
#pragma unroll
  for (int i = 0; i < 16; ++i) {
    int m = b + i * 4;
    out[(size_t)(m0 + m) * KDIM + d0 + a] = tile[m][a];
  }
}

// ---------------------------------------------------------------------------
// 2) GEMM: C[m][n] = (1/16) * sum_k A[m][k]*B[n][k],  M=N=8192, K=256, f16 out
//    256x128 tile, 4 waves (2x2) of 128x64, BK=32, XOR-swizzled LDS,
//    global_load_lds width-16 staging (linear dest + pre-swizzled source).
// ---------------------------------------------------------------------------
#define GLD16(gp, lp)                                                          \
  __builtin_amdgcn_global_load_lds(                                            \
      (const __attribute__((address_space(1))) void*)(gp),                     \
      (__attribute__((address_space(3))) void*)(lp), 16, 0, 0)

__global__ __launch_bounds__(256, 2) void corr_gemm(const f16* __restrict__ A,
                                                    const f16* __restrict__ B,
                                                    f16* __restrict__ C) {
  __shared__ f16 sA[256 * 32];   // 16KB, [row][k] with slot-swizzle
  __shared__ f16 sB[128 * 32];   // 8KB

  int bid = blockIdx.x;                       // 2048 blocks (32 bm x 64 bn)
  int swz = ((bid & 7) << 8) | (bid >> 3);    // XCD swizzle (2048%8==0 -> bijective)
  int bm = (swz >> 6) << 8;                   // 0..31 * 256
  int bn = (swz & 63) << 7;                   // 0..63 * 128

  int t = threadIdx.x;
  int lane = t & 63;
  int w = t >> 6;                 // wave 0..3
  int wm = (w >> 1) * 128;
  int wn = (w & 1) * 64;
  int lr = lane & 15;             // fragment row within 16
  int ko = lane >> 4;             // k-octet 0..3
  int xv = (lr & 3) ^ ((lr >> 2) & 1);   // row-swizzle term (rows == lr mod 16-mult)
  int rslot = (ko ^ xv) * 8;             // swizzled k-octet (f16 units)

  // staging: thread t owns LDS row r=t>>2 (+64*i), slot t&3 (linear dest);
  // source k-octet is pre-swizzled so LDS(r,s) holds global slot s^x(r)
  int xw = ((t >> 2) & 3) ^ ((t >> 4) & 1);
  int sslot = ((t & 3) ^ xw) * 8;
  const f16* Ab = A + (size_t)(bm + (t >> 2)) * KDIM + sslot;
  const f16* Bb = B + (size_t)(bn + (t >> 2)) * KDIM + sslot;

  f32x4 acc[8][4];
#pragma unroll
  for (int i = 0; i < 8; ++i)
#pragma unroll
    for (int j = 0; j < 4; ++j) acc[i][j] = (f32x4){0.f, 0.f, 0.f, 0.f};

#pragma unroll
  for (int k0 = 0; k0 < KDIM; k0 += 32) {
    GLD16(Ab + k0,                      sA + t * 8);
    GLD16(Ab + (size_t)64 * KDIM + k0,  sA + 2048 + t * 8);
    GLD16(Ab + (size_t)128 * KDIM + k0, sA + 4096 + t * 8);
    GLD16(Ab + (size_t)192 * KDIM + k0, sA + 6144 + t * 8);
    GLD16(Bb + k0,                      sB + t * 8);
    GLD16(Bb + (size_t)64 * KDIM + k0,  sB + 2048 + t * 8);
    __syncthreads();   // drains vmcnt -> LDS tiles valid

    f16x8 af[8], bf[4];
#pragma unroll
    for (int i = 0; i < 8; ++i)
      af[i] = *(const f16x8*)(sA + (wm + i * 16 + lr) * 32 + rslot);
#pragma unroll
    for (int i = 0; i < 4; ++i)
      bf[i] = *(const f16x8*)(sB + (wn + i * 16 + lr) * 32 + rslot);
#pragma unroll
    for (int mi = 0; mi < 8; ++mi)
#pragma unroll
      for (int ni = 0; ni < 4; ++ni)
        acc[mi][ni] = __builtin_amdgcn_mfma_f32_16x16x32_f16(af[mi], bf[ni],
                                                             acc[mi][ni], 0, 0, 0);
    __syncthreads();
  }

  // epilogue: D[row=ko*4+r2][col=lr] per fragment, scale 1/sqrt(256)
#pragma unroll
  for (int mi = 0; mi < 8; ++mi)
#pragma unroll
    for (int ni = 0; ni < 4; ++ni)
#pragma unroll
      for (int r2 = 0; r2 < 4; ++r2) {
        int row = bm + wm + mi * 16 + ko * 4 + r2;
        int col = bn + wn + ni * 16 + lr;
        C[(size_t)row * NPIX + col] = (f16)(acc[mi][ni][r2] * 0.0625f);
      }
}

// ---------------------------------------------------------------------------
// 3) fused pyramid pooling: thread owns an 8x8 block of L0 for one row m,
//    emits 4x4 of L1, 2x2 of L2, 1 of L3
// ---------------------------------------------------------------------------
__global__ __launch_bounds__(256) void pool_all(const f16* __restrict__ L0,
                                                f16* __restrict__ L1,
                                                f16* __restrict__ L2,
                                                f16* __restrict__ L3) {
  int idx = blockIdx.x * 256 + threadIdx.x;  // 1,048,576
  int x3 = idx & 15;
  int y3 = (idx >> 4) & 7;
  int n  = idx >> 7;
  const f16* base = L0 + (size_t)n * NPIX + y3 * 8 * W0 + x3 * 8;

  float v[8][8];
#pragma unroll
  for (int rr = 0; rr < 8; ++rr) {
    f16x8 row = *(const f16x8*)(base + rr * W0);
#pragma unroll
    for (int cc = 0; cc < 8; ++cc) v[rr][cc] = (float)row[cc];
  }

  float l1[4][4];
#pragma unroll
  for (int rr = 0; rr < 4; ++rr)
#pragma unroll
    for (int cc = 0; cc < 4; ++cc)
      l1[rr][cc] = 0.25f * (v[2*rr][2*cc] + v[2*rr][2*cc+1] +
                            v[2*rr+1][2*cc] + v[2*rr+1][2*cc+1]);
#pragma unroll
  for (int rr = 0; rr < 4; ++rr) {
    f16x4 o = {(f16)l1[rr][0], (f16)l1[rr][1], (f16)l1[rr][2], (f16)l1[rr][3]};
    *(f16x4*)(L1 + ((size_t)n * 32 + y3 * 4 + rr) * 64 + x3 * 4) = o;
  }

  float l2[2][2];
#pragma unroll
  for (int rr = 0; rr < 2; ++rr)
#pragma unroll
    for (int cc = 0; cc < 2; ++cc)
      l2[rr][cc] = 0.25f * (l1[2*rr][2*cc] + l1[2*rr][2*cc+1] +
                            l1[2*rr+1][2*cc] + l1[2*rr+1][2*cc+1]);
#pragma unroll
  for (int rr = 0; rr < 2; ++rr) {
    f16x2 o = {(f16)l2[rr][0], (f16)l2[rr][1]};
    *(f16x2*)(L2 + ((size_t)n * 16 + y3 * 2 + rr) * 32 + x3 * 2) = o;
  }

  float l3 = 0.25f * (l2[0][0] + l2[0][1] + l2[1][0] + l2[1][1]);
  L3[((size_t)n * 8 + y3) * 16 + x3] = (f16)l3;
}

// ---------------------------------------------------------------------------
// 4) bilinear window sampling, split by window row j for 9x parallelism.
//    grid (32, 9, 4): m coalesced, j = window row, lev = pyramid level.
// ---------------------------------------------------------------------------
__global__ __launch_bounds__(256) void corr_sample(const f16* __restrict__ P0,
                                                   const f16* __restrict__ P1,
                                                   const f16* __restrict__ P2,
                                                   const f16* __restrict__ P3,
                                                   const float* __restrict__ coords,
                                                   float* __restrict__ out) {
  int m = blockIdx.x * 256 + threadIdx.x;
  int j = blockIdx.y;       // window row 0..8
  int lev = blockIdx.z;     // 0..3
  const f16* P; int Hl, Wl;
  if (lev == 0)      { P = P0; Hl = 64; Wl = 128; }
  else if (lev == 1) { P = P1; Hl = 32; Wl = 64; }
  else if (lev == 2) { P = P2; Hl = 16; Wl = 32; }
  else               { P = P3; Hl = 8;  Wl = 16; }

  float cx = coords[m];
  float cy = coords[NPIX + m];
  float inv = 1.0f / (float)(1 << lev);
  float xb = cx * inv, yb = cy * inv;
  float fx = floorf(xb), fy = floorf(yb);
  int X0 = (int)fx - 4, Y0 = (int)fy - 4;
  float wx1 = xb - fx, wx0 = 1.0f - wx1;
  float wy1 = yb - fy, wy0 = 1.0f - wy1;

  const f16* base = P + (size_t)m * Hl * Wl;
  float* op = out + ((size_t)lev * 81 + (size_t)j * 9) * NPIX + m;

  float cur[10], nxt[10];
  {
    int y = Y0 + j;
    bool yin = (y >= 0) && (y < Hl);
    const f16* rp = base + y * Wl;
#pragma unroll
    for (int i = 0; i < 10; ++i) {
      int x = X0 + i;
      cur[i] = (yin && x >= 0 && x < Wl) ? (float)rp[x] : 0.0f;
    }
  }
  {
    int y = Y0 + j + 1;
    bool yin = (y >= 0) && (y < Hl);
    const f16* rp = base + y * Wl;
#pragma unroll
    for (int i = 0; i < 10; ++i) {
      int x = X0 + i;
      nxt[i] = (yin && x >= 0 && x < Wl) ? (float)rp[x] : 0.0f;
    }
  }
#pragma unroll
  for (int i = 0; i < 9; ++i) {
    float v = wy0 * (wx0 * cur[i] + wx1 * cur[i + 1])
            + wy1 * (wx0 * nxt[i] + wx1 * nxt[i + 1]);
    op[(size_t)i * NPIX] = v;
  }
}

// ---------------------------------------------------------------------------
extern "C" void kernel_launch(void* const* d_in, const int* in_sizes, int n_in,
                              void* d_out, int out_size, void* d_ws, size_t ws_size,
                              hipStream_t stream) {
  const float* fmap1  = (const float*)d_in[0];   // [1,256,64,128]
  const float* fmap2  = (const float*)d_in[1];
  const float* coords = (const float*)d_in[2];   // [1,2,64,128]
  float* out = (float*)d_out;                    // [1,324,64,128] fp32

  char* ws = (char*)d_ws;
  size_t offA  = 0;
  size_t offB  = offA  + (size_t)NPIX * KDIM * 2;      // 4 MB
  size_t offL0 = offB  + (size_t)NPIX * KDIM * 2;      // 8 MB
  size_t offL1 = offL0 + (size_t)NPIX * NPIX * 2;      // +128 MB
  size_t offL2 = offL1 + (size_t)NPIX * 2048 * 2;      // +32 MB
  size_t offL3 = offL2 + (size_t)NPIX * 512 * 2;       // +8 MB
  size_t need  = offL3 + (size_t)NPIX * 128 * 2;       // +2 MB  => ~187 MB
  if (ws_size < need) return;

  f16* A  = (f16*)(ws + offA);
  f16* B  = (f16*)(ws + offB);
  f16* L0 = (f16*)(ws + offL0);
  f16* L1 = (f16*)(ws + offL1);
  f16* L2 = (f16*)(ws + offL2);
  f16* L3 = (f16*)(ws + offL3);

  transpose_cvt<<<dim3(128, 4), 256, 0, stream>>>(fmap1, A);
  transpose_cvt<<<dim3(128, 4), 256, 0, stream>>>(fmap2, B);
  corr_gemm<<<2048, 256, 0, stream>>>(A, B, L0);
  pool_all<<<4096, 256, 0, stream>>>(L0, L1, L2, L3);
  corr_sample<<<dim3(32, 9, 4), 256, 0, stream>>>(L0, L1, L2, L3, coords, out);
}